// Round 8
// baseline (77.855 us; speedup 1.0000x reference)
//
#include <hip/hip_runtime.h>
#include <math.h>

#define NROWS 8192
#define DIM 64
#define KNBR 200
#define BN_EPS 1e-5f
#define BIGF 3.402823466e38f

// ---------- wave-level helpers (wave = 64 lanes) ----------

__device__ __forceinline__ float matvec64(const float* xlds,
                                          const float* __restrict__ W,
                                          int lane) {
    float acc = 0.f;
#pragma unroll
    for (int i4 = 0; i4 < 16; ++i4) {
        float4 xv = *(const float4*)(xlds + i4 * 4);
        acc = fmaf(xv.x, W[(i4 * 4 + 0) * 64 + lane], acc);
        acc = fmaf(xv.y, W[(i4 * 4 + 1) * 64 + lane], acc);
        acc = fmaf(xv.z, W[(i4 * 4 + 2) * 64 + lane], acc);
        acc = fmaf(xv.w, W[(i4 * 4 + 3) * 64 + lane], acc);
    }
    return acc;
}

__device__ __forceinline__ float matvec128(const float* xlds,
                                           const float* __restrict__ W,
                                           int lane) {
    float acc = 0.f;
#pragma unroll
    for (int i4 = 0; i4 < 32; ++i4) {
        float4 xv = *(const float4*)(xlds + i4 * 4);
        acc = fmaf(xv.x, W[(i4 * 4 + 0) * 64 + lane], acc);
        acc = fmaf(xv.y, W[(i4 * 4 + 1) * 64 + lane], acc);
        acc = fmaf(xv.z, W[(i4 * 4 + 2) * 64 + lane], acc);
        acc = fmaf(xv.w, W[(i4 * 4 + 3) * 64 + lane], acc);
    }
    return acc;
}

__device__ __forceinline__ float d2part(const float4 a, const float4 b) {
    const float dx = a.x - b.x, dy = a.y - b.y, dz = a.z - b.z, dw = a.w - b.w;
    float d2 = dx * dx;
    d2 = fmaf(dy, dy, d2);
    d2 = fmaf(dz, dz, d2);
    d2 = fmaf(dw, dw, d2);
    return d2;
}

// ---------- heterogeneous fused kernel ----------
// blockIdx.x < NROWS: GATHER block -- block = one row, wave w = chunk of 64
//   neighbors (slots w*64 .. w*64+63, clamped). Quad layout: 4 lanes own one
//   neighbor; lane reads float4s {sub, sub+4, sub+8, sub+12} of its row.
//   16 gather loads + 4 idx loads all in flight per wave.
// blockIdx.x >= NROWS: MLP block -- 4 rows, one wave each (round-2 form).
// launch_bounds(256, 8): 8 workgroups/CU -> full 32 waves/CU residency
// (round 7's (256,4) silently capped occupancy at 50%).
__global__ __launch_bounds__(256, 8) void fused_main(
    const float* __restrict__ v_embed,
    const float* __restrict__ u1p, const float* __restrict__ u2p,
    const float* __restrict__ u3p, const float* __restrict__ u4p,
    const float* __restrict__ evp,
    const float* __restrict__ w_ur1, const float* __restrict__ b_ur1,
    const float* __restrict__ w_ur2, const float* __restrict__ b_ur2,
    const float* __restrict__ w_vr1, const float* __restrict__ b_vr1,
    const float* __restrict__ w_vr2, const float* __restrict__ b_vr2,
    const float* __restrict__ w_uv1, const float* __restrict__ b_uv1,
    const float* __restrict__ w_uv2, const float* __restrict__ b_uv2,
    const float* __restrict__ w_uv3, const float* __restrict__ b_uv3,
    const float* __restrict__ bn1_g, const float* __restrict__ bn1_b,
    const float* __restrict__ bn1_m, const float* __restrict__ bn1_v,
    const float* __restrict__ bn2_g, const float* __restrict__ bn2_b,
    const float* __restrict__ bn2_m, const float* __restrict__ bn2_v,
    const float* __restrict__ bn3_g, const float* __restrict__ bn3_b,
    const float* __restrict__ bn3_m, const float* __restrict__ bn3_v,
    const float* __restrict__ bn4_g, const float* __restrict__ bn4_b,
    const float* __restrict__ bn4_m, const float* __restrict__ bn4_v,
    const int* __restrict__ nodes_v, const int* __restrict__ nbr_idx,
    const int* __restrict__ nbr_len,
    float* __restrict__ out_score, float* __restrict__ ws_d2,
    float* __restrict__ ws_c) {
    const int w = threadIdx.x >> 6;
    const int lane = threadIdx.x & 63;

    __shared__ float xbuf[4][132];
    __shared__ float pr[4];

    if (blockIdx.x < NROWS) {
        // ================= GATHER block =================
        const int row = blockIdx.x;              // block-uniform -> s_loads
        int len = nbr_len[row];
        if (len < 1) len = 1;
        const int c = w;                         // chunk = wave id
        float dmin2 = BIGF;
        if (c * 64 < len) {
            const int lenm1 = len - 1;
            const int q16 = lane >> 2;           // neighbor within group (0..15)
            const int sub = lane & 3;            // quad sub-lane
            const int node = nodes_v[row];
            const float4* vrow = (const float4*)(v_embed + ((size_t)node << 6));
            const float4 q0 = vrow[sub + 0];
            const float4 q1 = vrow[sub + 4];
            const float4 q2 = vrow[sub + 8];
            const float4 q3 = vrow[sub + 12];
            const int* nb = nbr_idx + (size_t)row * KNBR;
            const int base = c * 64 + q16;
            int n0 = base;           n0 = n0 < lenm1 ? n0 : lenm1;
            int n1 = base + 16;      n1 = n1 < lenm1 ? n1 : lenm1;
            int n2 = base + 32;      n2 = n2 < lenm1 ? n2 : lenm1;
            int n3 = base + 48;      n3 = n3 < lenm1 ? n3 : lenm1;
            const int i0 = nb[n0];
            const int i1 = nb[n1];
            const int i2 = nb[n2];
            const int i3 = nb[n3];
            const float4* r0 = (const float4*)(v_embed + ((size_t)i0 << 6));
            const float4* r1 = (const float4*)(v_embed + ((size_t)i1 << 6));
            const float4* r2 = (const float4*)(v_embed + ((size_t)i2 << 6));
            const float4* r3 = (const float4*)(v_embed + ((size_t)i3 << 6));
            // 16 independent gathers in flight
            const float4 a00 = r0[sub + 0], a01 = r0[sub + 4], a02 = r0[sub + 8], a03 = r0[sub + 12];
            const float4 a10 = r1[sub + 0], a11 = r1[sub + 4], a12 = r1[sub + 8], a13 = r1[sub + 12];
            const float4 a20 = r2[sub + 0], a21 = r2[sub + 4], a22 = r2[sub + 8], a23 = r2[sub + 12];
            const float4 a30 = r3[sub + 0], a31 = r3[sub + 4], a32 = r3[sub + 8], a33 = r3[sub + 12];
            float d0 = d2part(q0, a00) + d2part(q1, a01) + d2part(q2, a02) + d2part(q3, a03);
            float d1 = d2part(q0, a10) + d2part(q1, a11) + d2part(q2, a12) + d2part(q3, a13);
            float d2 = d2part(q0, a20) + d2part(q1, a21) + d2part(q2, a22) + d2part(q3, a23);
            float d3 = d2part(q0, a30) + d2part(q1, a31) + d2part(q2, a32) + d2part(q3, a33);
            // quad-sum: after xor1+xor2 every lane of the quad has full d^2
            d0 += __shfl_xor(d0, 1); d0 += __shfl_xor(d0, 2);
            d1 += __shfl_xor(d1, 1); d1 += __shfl_xor(d1, 2);
            d2 += __shfl_xor(d2, 1); d2 += __shfl_xor(d2, 2);
            d3 += __shfl_xor(d3, 1); d3 += __shfl_xor(d3, 2);
            dmin2 = fminf(fminf(d0, d1), fminf(d2, d3));
        }
        // cross-quad wave reduce (quads hold equal values -> start at 4)
        dmin2 = fminf(dmin2, __shfl_xor(dmin2, 4));
        dmin2 = fminf(dmin2, __shfl_xor(dmin2, 8));
        dmin2 = fminf(dmin2, __shfl_xor(dmin2, 16));
        dmin2 = fminf(dmin2, __shfl_xor(dmin2, 32));
        if (lane == 0) pr[w] = dmin2;
        __syncthreads();
        if (threadIdx.x == 0) {
            ws_d2[row] = fminf(fminf(pr[0], pr[1]), fminf(pr[2], pr[3]));
        }
        return;
    }

    // ================= MLP block: 4 rows, one wave each =================
    const int row = (blockIdx.x - NROWS) * 4 + w;
    float* xw = xbuf[w];
    const size_t rb = (size_t)row * DIM + lane;
    const float u1 = u1p[rb], u2 = u2p[rb], u3 = u3p[rb], u4 = u4p[rb];
    const float ev = evp[rb];

    float d12 = u1 - u2, d23 = u2 - u3, d34 = u3 - u4;
    float s1 = d12 * d12, s2 = d23 * d23, s3 = d34 * d34;
#pragma unroll
    for (int m = 1; m < 64; m <<= 1) {
        s1 += __shfl_xor(s1, m);
        s2 += __shfl_xor(s2, m);
        s3 += __shfl_xor(s3, m);
    }
    const float cval = (sqrtf(s1) + sqrtf(s2) + sqrtf(s3)) * (1.0f / 3.0f);

    float eu = u1 * 0.032058603280084993f;
    eu = fmaf(u2, 0.087144318742032567f, eu);
    eu = fmaf(u3, 0.236882818089910134f, eu);
    eu = fmaf(u4, 0.643914259887972245f, eu);

    xw[lane] = eu;
    float t1 = matvec64(xw, w_ur1, lane) + b_ur1[lane];
    t1 = (t1 - bn1_m[lane]) * rsqrtf(bn1_v[lane] + BN_EPS) * bn1_g[lane] + bn1_b[lane];
    t1 = fmaxf(t1, 0.f);
    xw[lane] = t1;
    const float xu = matvec64(xw, w_ur2, lane) + b_ur2[lane];
    xw[lane] = ev;
    float t2 = matvec64(xw, w_vr1, lane) + b_vr1[lane];
    t2 = (t2 - bn2_m[lane]) * rsqrtf(bn2_v[lane] + BN_EPS) * bn2_g[lane] + bn2_b[lane];
    t2 = fmaxf(t2, 0.f);
    xw[lane] = t2;
    const float xv = matvec64(xw, w_vr2, lane) + b_vr2[lane];
    xw[lane] = xu;
    xw[64 + lane] = xv;
    float t3 = matvec128(xw, w_uv1, lane) + b_uv1[lane];
    t3 = (t3 - bn3_m[lane]) * rsqrtf(bn3_v[lane] + BN_EPS) * bn3_g[lane] + bn3_b[lane];
    t3 = fmaxf(t3, 0.f);
    xw[lane] = t3;
    const int jj = lane & 15;
    const int q = lane >> 4;
    float h4 = 0.f;
#pragma unroll
    for (int i = 0; i < 16; ++i) {
        h4 = fmaf(xw[q * 16 + i], w_uv2[(q * 16 + i) * 16 + jj], h4);
    }
    h4 += __shfl_xor(h4, 16);
    h4 += __shfl_xor(h4, 32);
    h4 += b_uv2[jj];
    h4 = (h4 - bn4_m[jj]) * rsqrtf(bn4_v[jj] + BN_EPS) * bn4_g[jj] + bn4_b[jj];
    h4 = fmaxf(h4, 0.f);
    float p = h4 * w_uv3[jj];
#pragma unroll
    for (int m = 1; m < 16; m <<= 1) p += __shfl_xor(p, m);
    const float score = p + b_uv3[0];

    if (lane == 0) {
        out_score[row] = score;
        ws_c[row] = cval;
    }
}

// ---------- final combine: single block, global min/max + outputs ----------
__global__ __launch_bounds__(1024) void combine(
    const float* __restrict__ ws_d2, const float* __restrict__ ws_c,
    float* __restrict__ out) {
    const int tid = threadIdx.x;
    __shared__ float red[4][16];

    float ld2[8], lc[8];
    float dmin = BIGF, dmax = -BIGF, cmin = BIGF, cmax = -BIGF;
#pragma unroll
    for (int i = 0; i < 8; ++i) {
        const int b = tid * 8 + i;  // 1024 * 8 == 8192
        ld2[i] = ws_d2[b];
        lc[i] = ws_c[b];
        dmin = fminf(dmin, ld2[i]);
        dmax = fmaxf(dmax, ld2[i]);
        cmin = fminf(cmin, lc[i]);
        cmax = fmaxf(cmax, lc[i]);
    }
#pragma unroll
    for (int m = 1; m < 64; m <<= 1) {
        dmin = fminf(dmin, __shfl_xor(dmin, m));
        dmax = fmaxf(dmax, __shfl_xor(dmax, m));
        cmin = fminf(cmin, __shfl_xor(cmin, m));
        cmax = fmaxf(cmax, __shfl_xor(cmax, m));
    }
    const int wid = tid >> 6;
    const int lane = tid & 63;
    if (lane == 0) {
        red[0][wid] = dmin;
        red[1][wid] = dmax;
        red[2][wid] = cmin;
        red[3][wid] = cmax;
    }
    __syncthreads();
    dmin = red[0][0]; dmax = red[1][0]; cmin = red[2][0]; cmax = red[3][0];
#pragma unroll
    for (int i = 1; i < 16; ++i) {
        dmin = fminf(dmin, red[0][i]);
        dmax = fmaxf(dmax, red[1][i]);
        cmin = fminf(cmin, red[2][i]);
        cmax = fmaxf(cmax, red[3][i]);
    }
    const float dlo = sqrtf(dmin);
    const float dhi = sqrtf(dmax);
    const float inv_d = 1.f / (dhi - dlo);
    const float inv_c = 1.f / (cmax - cmin);
#pragma unroll
    for (int i = 0; i < 8; ++i) {
        const int b = tid * 8 + i;
        const float t = (sqrtf(ld2[i]) - dlo) * inv_d;
        const float unexp = 6.f * t * expf(-6.f * t);
        out[b] += unexp * (lc[i] - cmin) * inv_c;
    }
}

extern "C" void kernel_launch(void* const* d_in, const int* in_sizes, int n_in,
                              void* d_out, int out_size, void* d_ws, size_t ws_size,
                              hipStream_t stream) {
    const float* v_embed = (const float*)d_in[0];
    const float* u1 = (const float*)d_in[1];
    const float* u2 = (const float*)d_in[2];
    const float* u3 = (const float*)d_in[3];
    const float* u4 = (const float*)d_in[4];
    const float* ev = (const float*)d_in[5];
    const float* w_ur1 = (const float*)d_in[6];
    const float* b_ur1 = (const float*)d_in[7];
    const float* w_ur2 = (const float*)d_in[8];
    const float* b_ur2 = (const float*)d_in[9];
    const float* w_vr1 = (const float*)d_in[10];
    const float* b_vr1 = (const float*)d_in[11];
    const float* w_vr2 = (const float*)d_in[12];
    const float* b_vr2 = (const float*)d_in[13];
    const float* w_uv1 = (const float*)d_in[14];
    const float* b_uv1 = (const float*)d_in[15];
    const float* w_uv2 = (const float*)d_in[16];
    const float* b_uv2 = (const float*)d_in[17];
    const float* w_uv3 = (const float*)d_in[18];
    const float* b_uv3 = (const float*)d_in[19];
    const int* nodes_v = (const int*)d_in[20];
    const int* nbr_idx = (const int*)d_in[21];
    const int* nbr_len = (const int*)d_in[22];
    const float* bn1_g = (const float*)d_in[23];
    const float* bn1_b = (const float*)d_in[24];
    const float* bn1_m = (const float*)d_in[25];
    const float* bn1_v = (const float*)d_in[26];
    const float* bn2_g = (const float*)d_in[27];
    const float* bn2_b = (const float*)d_in[28];
    const float* bn2_m = (const float*)d_in[29];
    const float* bn2_v = (const float*)d_in[30];
    const float* bn3_g = (const float*)d_in[31];
    const float* bn3_b = (const float*)d_in[32];
    const float* bn3_m = (const float*)d_in[33];
    const float* bn3_v = (const float*)d_in[34];
    const float* bn4_g = (const float*)d_in[35];
    const float* bn4_b = (const float*)d_in[36];
    const float* bn4_m = (const float*)d_in[37];
    const float* bn4_v = (const float*)d_in[38];

    float* out = (float*)d_out;
    float* wsf = (float*)d_ws;
    float* ws_d2 = wsf;
    float* ws_c = wsf + NROWS;

    // blocks [0, NROWS): gather (1 row, 4 chunk-waves);
    // blocks [NROWS, NROWS + NROWS/4): MLP (4 rows each)
    hipLaunchKernelGGL(fused_main, dim3(NROWS + NROWS / 4), dim3(256), 0, stream,
                       v_embed, u1, u2, u3, u4, ev,
                       w_ur1, b_ur1, w_ur2, b_ur2, w_vr1, b_vr1, w_vr2, b_vr2,
                       w_uv1, b_uv1, w_uv2, b_uv2, w_uv3, b_uv3,
                       bn1_g, bn1_b, bn1_m, bn1_v,
                       bn2_g, bn2_b, bn2_m, bn2_v,
                       bn3_g, bn3_b, bn3_m, bn3_v,
                       bn4_g, bn4_b, bn4_m, bn4_v,
                       nodes_v, nbr_idx, nbr_len,
                       out, ws_d2, ws_c);
    hipLaunchKernelGGL(combine, dim3(1), dim3(1024), 0, stream,
                       ws_d2, ws_c, out);
}

// Round 9
// 63.241 us; speedup vs baseline: 1.2311x; 1.2311x over previous
//
#include <hip/hip_runtime.h>
#include <math.h>

#define NROWS 8192
#define DIM 64
#define KNBR 200
#define BN_EPS 1e-5f
#define BIGF 3.402823466e38f

// ---------- wave-level helpers (wave = 64 lanes) ----------

__device__ __forceinline__ float matvec64(const float* xlds,
                                          const float* __restrict__ W,
                                          int lane) {
    float acc = 0.f;
#pragma unroll
    for (int i4 = 0; i4 < 16; ++i4) {
        float4 xv = *(const float4*)(xlds + i4 * 4);
        acc = fmaf(xv.x, W[(i4 * 4 + 0) * 64 + lane], acc);
        acc = fmaf(xv.y, W[(i4 * 4 + 1) * 64 + lane], acc);
        acc = fmaf(xv.z, W[(i4 * 4 + 2) * 64 + lane], acc);
        acc = fmaf(xv.w, W[(i4 * 4 + 3) * 64 + lane], acc);
    }
    return acc;
}

__device__ __forceinline__ float matvec128(const float* xlds,
                                           const float* __restrict__ W,
                                           int lane) {
    float acc = 0.f;
#pragma unroll
    for (int i4 = 0; i4 < 32; ++i4) {
        float4 xv = *(const float4*)(xlds + i4 * 4);
        acc = fmaf(xv.x, W[(i4 * 4 + 0) * 64 + lane], acc);
        acc = fmaf(xv.y, W[(i4 * 4 + 1) * 64 + lane], acc);
        acc = fmaf(xv.z, W[(i4 * 4 + 2) * 64 + lane], acc);
        acc = fmaf(xv.w, W[(i4 * 4 + 3) * 64 + lane], acc);
    }
    return acc;
}

__device__ __forceinline__ float d2part(const float4 a, const float4 b) {
    const float dx = a.x - b.x, dy = a.y - b.y, dz = a.z - b.z, dw = a.w - b.w;
    float d2 = dx * dx;
    d2 = fmaf(dy, dy, d2);
    d2 = fmaf(dz, dz, d2);
    d2 = fmaf(dw, dw, d2);
    return d2;
}

// ---------- heterogeneous fused kernel ----------
// blockIdx.x < NROWS: GATHER block -- block = one row, wave w = chunk of 64
//   neighbors (slots w*64 .. w*64+63, clamped). Quad layout: 4 lanes own one
//   neighbor; lane reads float4s {sub, sub+4, sub+8, sub+12} of its row.
//   16 gather loads + 4 idx loads all in flight per wave.
// blockIdx.x >= NROWS: MLP block -- 4 rows, one wave each (round-2 form).
// NOTE: plain __launch_bounds__(256). R7's (256,4) capped occupancy at 50%;
// R8's (256,8) forced VGPR 96->32 and spilled 70 MB/launch to scratch.
// At ~48 VGPR the HW can resident 8 blocks/CU on its own; the 10240-block
// grid provides the backfill pool.
__global__ __launch_bounds__(256) void fused_main(
    const float* __restrict__ v_embed,
    const float* __restrict__ u1p, const float* __restrict__ u2p,
    const float* __restrict__ u3p, const float* __restrict__ u4p,
    const float* __restrict__ evp,
    const float* __restrict__ w_ur1, const float* __restrict__ b_ur1,
    const float* __restrict__ w_ur2, const float* __restrict__ b_ur2,
    const float* __restrict__ w_vr1, const float* __restrict__ b_vr1,
    const float* __restrict__ w_vr2, const float* __restrict__ b_vr2,
    const float* __restrict__ w_uv1, const float* __restrict__ b_uv1,
    const float* __restrict__ w_uv2, const float* __restrict__ b_uv2,
    const float* __restrict__ w_uv3, const float* __restrict__ b_uv3,
    const float* __restrict__ bn1_g, const float* __restrict__ bn1_b,
    const float* __restrict__ bn1_m, const float* __restrict__ bn1_v,
    const float* __restrict__ bn2_g, const float* __restrict__ bn2_b,
    const float* __restrict__ bn2_m, const float* __restrict__ bn2_v,
    const float* __restrict__ bn3_g, const float* __restrict__ bn3_b,
    const float* __restrict__ bn3_m, const float* __restrict__ bn3_v,
    const float* __restrict__ bn4_g, const float* __restrict__ bn4_b,
    const float* __restrict__ bn4_m, const float* __restrict__ bn4_v,
    const int* __restrict__ nodes_v, const int* __restrict__ nbr_idx,
    const int* __restrict__ nbr_len,
    float* __restrict__ out_score, float* __restrict__ ws_d2,
    float* __restrict__ ws_c) {
    const int w = threadIdx.x >> 6;
    const int lane = threadIdx.x & 63;

    __shared__ float xbuf[4][132];
    __shared__ float pr[4];

    if (blockIdx.x < NROWS) {
        // ================= GATHER block =================
        const int row = blockIdx.x;              // block-uniform -> s_loads
        int len = nbr_len[row];
        if (len < 1) len = 1;
        const int c = w;                         // chunk = wave id
        float dmin2 = BIGF;
        if (c * 64 < len) {
            const int lenm1 = len - 1;
            const int q16 = lane >> 2;           // neighbor within group (0..15)
            const int sub = lane & 3;            // quad sub-lane
            const int node = nodes_v[row];
            const float4* vrow = (const float4*)(v_embed + ((size_t)node << 6));
            const float4 q0 = vrow[sub + 0];
            const float4 q1 = vrow[sub + 4];
            const float4 q2 = vrow[sub + 8];
            const float4 q3 = vrow[sub + 12];
            const int* nb = nbr_idx + (size_t)row * KNBR;
            const int base = c * 64 + q16;
            int n0 = base;           n0 = n0 < lenm1 ? n0 : lenm1;
            int n1 = base + 16;      n1 = n1 < lenm1 ? n1 : lenm1;
            int n2 = base + 32;      n2 = n2 < lenm1 ? n2 : lenm1;
            int n3 = base + 48;      n3 = n3 < lenm1 ? n3 : lenm1;
            const int i0 = nb[n0];
            const int i1 = nb[n1];
            const int i2 = nb[n2];
            const int i3 = nb[n3];
            const float4* r0 = (const float4*)(v_embed + ((size_t)i0 << 6));
            const float4* r1 = (const float4*)(v_embed + ((size_t)i1 << 6));
            const float4* r2 = (const float4*)(v_embed + ((size_t)i2 << 6));
            const float4* r3 = (const float4*)(v_embed + ((size_t)i3 << 6));
            // 16 independent gathers in flight
            const float4 a00 = r0[sub + 0], a01 = r0[sub + 4], a02 = r0[sub + 8], a03 = r0[sub + 12];
            const float4 a10 = r1[sub + 0], a11 = r1[sub + 4], a12 = r1[sub + 8], a13 = r1[sub + 12];
            const float4 a20 = r2[sub + 0], a21 = r2[sub + 4], a22 = r2[sub + 8], a23 = r2[sub + 12];
            const float4 a30 = r3[sub + 0], a31 = r3[sub + 4], a32 = r3[sub + 8], a33 = r3[sub + 12];
            float d0 = d2part(q0, a00) + d2part(q1, a01) + d2part(q2, a02) + d2part(q3, a03);
            float d1 = d2part(q0, a10) + d2part(q1, a11) + d2part(q2, a12) + d2part(q3, a13);
            float d2 = d2part(q0, a20) + d2part(q1, a21) + d2part(q2, a22) + d2part(q3, a23);
            float d3 = d2part(q0, a30) + d2part(q1, a31) + d2part(q2, a32) + d2part(q3, a33);
            // quad-sum: after xor1+xor2 every lane of the quad has full d^2
            d0 += __shfl_xor(d0, 1); d0 += __shfl_xor(d0, 2);
            d1 += __shfl_xor(d1, 1); d1 += __shfl_xor(d1, 2);
            d2 += __shfl_xor(d2, 1); d2 += __shfl_xor(d2, 2);
            d3 += __shfl_xor(d3, 1); d3 += __shfl_xor(d3, 2);
            dmin2 = fminf(fminf(d0, d1), fminf(d2, d3));
        }
        // cross-quad wave reduce (quads hold equal values -> start at 4)
        dmin2 = fminf(dmin2, __shfl_xor(dmin2, 4));
        dmin2 = fminf(dmin2, __shfl_xor(dmin2, 8));
        dmin2 = fminf(dmin2, __shfl_xor(dmin2, 16));
        dmin2 = fminf(dmin2, __shfl_xor(dmin2, 32));
        if (lane == 0) pr[w] = dmin2;
        __syncthreads();
        if (threadIdx.x == 0) {
            ws_d2[row] = fminf(fminf(pr[0], pr[1]), fminf(pr[2], pr[3]));
        }
        return;
    }

    // ================= MLP block: 4 rows, one wave each =================
    const int row = (blockIdx.x - NROWS) * 4 + w;
    float* xw = xbuf[w];
    const size_t rb = (size_t)row * DIM + lane;
    const float u1 = u1p[rb], u2 = u2p[rb], u3 = u3p[rb], u4 = u4p[rb];
    const float ev = evp[rb];

    float d12 = u1 - u2, d23 = u2 - u3, d34 = u3 - u4;
    float s1 = d12 * d12, s2 = d23 * d23, s3 = d34 * d34;
#pragma unroll
    for (int m = 1; m < 64; m <<= 1) {
        s1 += __shfl_xor(s1, m);
        s2 += __shfl_xor(s2, m);
        s3 += __shfl_xor(s3, m);
    }
    const float cval = (sqrtf(s1) + sqrtf(s2) + sqrtf(s3)) * (1.0f / 3.0f);

    float eu = u1 * 0.032058603280084993f;
    eu = fmaf(u2, 0.087144318742032567f, eu);
    eu = fmaf(u3, 0.236882818089910134f, eu);
    eu = fmaf(u4, 0.643914259887972245f, eu);

    xw[lane] = eu;
    float t1 = matvec64(xw, w_ur1, lane) + b_ur1[lane];
    t1 = (t1 - bn1_m[lane]) * rsqrtf(bn1_v[lane] + BN_EPS) * bn1_g[lane] + bn1_b[lane];
    t1 = fmaxf(t1, 0.f);
    xw[lane] = t1;
    const float xu = matvec64(xw, w_ur2, lane) + b_ur2[lane];
    xw[lane] = ev;
    float t2 = matvec64(xw, w_vr1, lane) + b_vr1[lane];
    t2 = (t2 - bn2_m[lane]) * rsqrtf(bn2_v[lane] + BN_EPS) * bn2_g[lane] + bn2_b[lane];
    t2 = fmaxf(t2, 0.f);
    xw[lane] = t2;
    const float xv = matvec64(xw, w_vr2, lane) + b_vr2[lane];
    xw[lane] = xu;
    xw[64 + lane] = xv;
    float t3 = matvec128(xw, w_uv1, lane) + b_uv1[lane];
    t3 = (t3 - bn3_m[lane]) * rsqrtf(bn3_v[lane] + BN_EPS) * bn3_g[lane] + bn3_b[lane];
    t3 = fmaxf(t3, 0.f);
    xw[lane] = t3;
    const int jj = lane & 15;
    const int q = lane >> 4;
    float h4 = 0.f;
#pragma unroll
    for (int i = 0; i < 16; ++i) {
        h4 = fmaf(xw[q * 16 + i], w_uv2[(q * 16 + i) * 16 + jj], h4);
    }
    h4 += __shfl_xor(h4, 16);
    h4 += __shfl_xor(h4, 32);
    h4 += b_uv2[jj];
    h4 = (h4 - bn4_m[jj]) * rsqrtf(bn4_v[jj] + BN_EPS) * bn4_g[jj] + bn4_b[jj];
    h4 = fmaxf(h4, 0.f);
    float p = h4 * w_uv3[jj];
#pragma unroll
    for (int m = 1; m < 16; m <<= 1) p += __shfl_xor(p, m);
    const float score = p + b_uv3[0];

    if (lane == 0) {
        out_score[row] = score;
        ws_c[row] = cval;
    }
}

// ---------- final combine: single block, global min/max + outputs ----------
__global__ __launch_bounds__(1024) void combine(
    const float* __restrict__ ws_d2, const float* __restrict__ ws_c,
    float* __restrict__ out) {
    const int tid = threadIdx.x;
    __shared__ float red[4][16];

    float ld2[8], lc[8];
    float dmin = BIGF, dmax = -BIGF, cmin = BIGF, cmax = -BIGF;
#pragma unroll
    for (int i = 0; i < 8; ++i) {
        const int b = tid * 8 + i;  // 1024 * 8 == 8192
        ld2[i] = ws_d2[b];
        lc[i] = ws_c[b];
        dmin = fminf(dmin, ld2[i]);
        dmax = fmaxf(dmax, ld2[i]);
        cmin = fminf(cmin, lc[i]);
        cmax = fmaxf(cmax, lc[i]);
    }
#pragma unroll
    for (int m = 1; m < 64; m <<= 1) {
        dmin = fminf(dmin, __shfl_xor(dmin, m));
        dmax = fmaxf(dmax, __shfl_xor(dmax, m));
        cmin = fminf(cmin, __shfl_xor(cmin, m));
        cmax = fmaxf(cmax, __shfl_xor(cmax, m));
    }
    const int wid = tid >> 6;
    const int lane = tid & 63;
    if (lane == 0) {
        red[0][wid] = dmin;
        red[1][wid] = dmax;
        red[2][wid] = cmin;
        red[3][wid] = cmax;
    }
    __syncthreads();
    dmin = red[0][0]; dmax = red[1][0]; cmin = red[2][0]; cmax = red[3][0];
#pragma unroll
    for (int i = 1; i < 16; ++i) {
        dmin = fminf(dmin, red[0][i]);
        dmax = fmaxf(dmax, red[1][i]);
        cmin = fminf(cmin, red[2][i]);
        cmax = fmaxf(cmax, red[3][i]);
    }
    const float dlo = sqrtf(dmin);
    const float dhi = sqrtf(dmax);
    const float inv_d = 1.f / (dhi - dlo);
    const float inv_c = 1.f / (cmax - cmin);
#pragma unroll
    for (int i = 0; i < 8; ++i) {
        const int b = tid * 8 + i;
        const float t = (sqrtf(ld2[i]) - dlo) * inv_d;
        const float unexp = 6.f * t * expf(-6.f * t);
        out[b] += unexp * (lc[i] - cmin) * inv_c;
    }
}

extern "C" void kernel_launch(void* const* d_in, const int* in_sizes, int n_in,
                              void* d_out, int out_size, void* d_ws, size_t ws_size,
                              hipStream_t stream) {
    const float* v_embed = (const float*)d_in[0];
    const float* u1 = (const float*)d_in[1];
    const float* u2 = (const float*)d_in[2];
    const float* u3 = (const float*)d_in[3];
    const float* u4 = (const float*)d_in[4];
    const float* ev = (const float*)d_in[5];
    const float* w_ur1 = (const float*)d_in[6];
    const float* b_ur1 = (const float*)d_in[7];
    const float* w_ur2 = (const float*)d_in[8];
    const float* b_ur2 = (const float*)d_in[9];
    const float* w_vr1 = (const float*)d_in[10];
    const float* b_vr1 = (const float*)d_in[11];
    const float* w_vr2 = (const float*)d_in[12];
    const float* b_vr2 = (const float*)d_in[13];
    const float* w_uv1 = (const float*)d_in[14];
    const float* b_uv1 = (const float*)d_in[15];
    const float* w_uv2 = (const float*)d_in[16];
    const float* b_uv2 = (const float*)d_in[17];
    const float* w_uv3 = (const float*)d_in[18];
    const float* b_uv3 = (const float*)d_in[19];
    const int* nodes_v = (const int*)d_in[20];
    const int* nbr_idx = (const int*)d_in[21];
    const int* nbr_len = (const int*)d_in[22];
    const float* bn1_g = (const float*)d_in[23];
    const float* bn1_b = (const float*)d_in[24];
    const float* bn1_m = (const float*)d_in[25];
    const float* bn1_v = (const float*)d_in[26];
    const float* bn2_g = (const float*)d_in[27];
    const float* bn2_b = (const float*)d_in[28];
    const float* bn2_m = (const float*)d_in[29];
    const float* bn2_v = (const float*)d_in[30];
    const float* bn3_g = (const float*)d_in[31];
    const float* bn3_b = (const float*)d_in[32];
    const float* bn3_m = (const float*)d_in[33];
    const float* bn3_v = (const float*)d_in[34];
    const float* bn4_g = (const float*)d_in[35];
    const float* bn4_b = (const float*)d_in[36];
    const float* bn4_m = (const float*)d_in[37];
    const float* bn4_v = (const float*)d_in[38];

    float* out = (float*)d_out;
    float* wsf = (float*)d_ws;
    float* ws_d2 = wsf;
    float* ws_c = wsf + NROWS;

    // blocks [0, NROWS): gather (1 row, 4 chunk-waves);
    // blocks [NROWS, NROWS + NROWS/4): MLP (4 rows each)
    hipLaunchKernelGGL(fused_main, dim3(NROWS + NROWS / 4), dim3(256), 0, stream,
                       v_embed, u1, u2, u3, u4, ev,
                       w_ur1, b_ur1, w_ur2, b_ur2, w_vr1, b_vr1, w_vr2, b_vr2,
                       w_uv1, b_uv1, w_uv2, b_uv2, w_uv3, b_uv3,
                       bn1_g, bn1_b, bn1_m, bn1_v,
                       bn2_g, bn2_b, bn2_m, bn2_v,
                       bn3_g, bn3_b, bn3_m, bn3_v,
                       bn4_g, bn4_b, bn4_m, bn4_v,
                       nodes_v, nbr_idx, nbr_len,
                       out, ws_d2, ws_c);
    hipLaunchKernelGGL(combine, dim3(1), dim3(1024), 0, stream,
                       ws_d2, ws_c, out);
}